// Round 1
// baseline (304.111 us; speedup 1.0000x reference)
//
#include <hip/hip_runtime.h>
#include <hip/hip_bf16.h>
#include <math.h>

typedef __bf16 bf16;
typedef __attribute__((ext_vector_type(8))) __bf16 bf16x8;
typedef __attribute__((ext_vector_type(4))) float f32x4;

#define EPSBN 1e-5f
#define B_    4096
#define N_    64
#define FIN_  67
#define E_    512
#define TOT_E 576
#define NSLOT 128

// ---------------- K0: build CSR (by dst) + norm, zero stat partials ----------------
__global__ __launch_bounds__(256) void k0_prep(const int* __restrict__ edge,
    float* __restrict__ partials,          // NSLOT*64*2 * 2 layers, contiguous
    int* __restrict__ g_off, int* __restrict__ g_src, float* __restrict__ g_nrm)
{
    int tid = threadIdx.x;
    for (int i = blockIdx.x * 256 + tid; i < NSLOT * 64 * 4; i += gridDim.x * 256)
        partials[i] = 0.f;
    if (blockIdx.x != 0) return;

    __shared__ int ssrc[TOT_E], sdst[TOT_E];
    __shared__ int deg[N_], cnt[N_], off[N_ + 1];
    __shared__ float dinv[N_];
    for (int i = tid; i < TOT_E; i += 256) {
        int s, d;
        if (i < E_) { s = edge[i]; d = edge[E_ + i]; }
        else        { s = i - E_; d = i - E_; }      // self loops
        ssrc[i] = s; sdst[i] = d;
    }
    if (tid < N_) { deg[tid] = 0; cnt[tid] = 0; }
    __syncthreads();
    for (int i = tid; i < TOT_E; i += 256) atomicAdd(&deg[sdst[i]], 1);
    __syncthreads();
    if (tid < N_) {                                   // wave 0 only: scan
        dinv[tid] = rsqrtf((float)deg[tid]);          // deg >= 1 (self loop)
        int v = deg[tid];
        for (int o = 1; o < 64; o <<= 1) { int u = __shfl_up(v, o); if (tid >= o) v += u; }
        off[tid] = v - deg[tid];
        if (tid == 63) off[N_] = v;
    }
    __syncthreads();
    for (int i = tid; i < TOT_E; i += 256) {
        int d = sdst[i];
        int p = off[d] + atomicAdd(&cnt[d], 1);
        g_src[p] = ssrc[i];
        g_nrm[p] = dinv[ssrc[i]] * dinv[d];
    }
    if (tid <= N_) g_off[tid] = off[tid];
}

// ---------------- K1: GCN layer 1 (matmul MFMA + aggregate + bias + stats) ----------------
__global__ __launch_bounds__(256) void k1_gcn1(
    const float* __restrict__ x,          // [B][64][67]
    const float* __restrict__ W1,         // [64][67]
    const float* __restrict__ b1,
    const int* __restrict__ g_off, const int* __restrict__ g_src,
    const float* __restrict__ g_nrm,
    bf16* __restrict__ g1out,             // [B][64][64]
    float* __restrict__ part1)            // [NSLOT][64][2]
{
    __shared__ union {
        struct { bf16 xa[64 * 104]; bf16 wb[64 * 104]; } s0;  // K padded 67->96, pitch 104
        struct { float hs[64 * 68]; } s1;                     // 64x64 h, pitch 68 (16B-aligned rows)
    } u;
    __shared__ int coff[N_ + 1];
    __shared__ int csrc[TOT_E];
    __shared__ float cnrm[TOT_E];

    int tid = threadIdx.x;
    int b = blockIdx.x;
    for (int i = tid; i <= N_; i += 256) coff[i] = g_off[i];
    for (int i = tid; i < TOT_E; i += 256) { csrc[i] = g_src[i]; cnrm[i] = g_nrm[i]; }

    const float* xb = x + (size_t)b * (N_ * FIN_);
    for (int i = tid; i < N_ * FIN_; i += 256) {
        int n = i / FIN_, f = i % FIN_;
        u.s0.xa[n * 104 + f] = (bf16)xb[i];
    }
    for (int i = tid; i < N_ * FIN_; i += 256) {
        int n = i / FIN_, f = i % FIN_;
        u.s0.wb[n * 104 + f] = (bf16)W1[i];
    }
    for (int i = tid; i < 64 * 29; i += 256) {        // zero pad k = 67..95
        int n = i / 29, f = 67 + i % 29;
        u.s0.xa[n * 104 + f] = (bf16)0.f;
        u.s0.wb[n * 104 + f] = (bf16)0.f;
    }
    __syncthreads();

    int w = tid >> 6, lane = tid & 63, q = lane >> 4, r15 = lane & 15;
    f32x4 z4 = {0.f, 0.f, 0.f, 0.f};
    f32x4 acc[4] = {z4, z4, z4, z4};
    int arow = w * 16 + r15;
#pragma unroll
    for (int kt = 0; kt < 3; ++kt) {
        bf16x8 a = *(const bf16x8*)&u.s0.xa[arow * 104 + kt * 32 + q * 8];
#pragma unroll
        for (int nt = 0; nt < 4; ++nt) {
            bf16x8 bb = *(const bf16x8*)&u.s0.wb[(nt * 16 + r15) * 104 + kt * 32 + q * 8];
            acc[nt] = __builtin_amdgcn_mfma_f32_16x16x32_bf16(a, bb, acc[nt], 0, 0, 0);
        }
    }
    __syncthreads();                                  // all xa/wb reads done before hs overwrite
#pragma unroll
    for (int nt = 0; nt < 4; ++nt)
#pragma unroll
        for (int r = 0; r < 4; ++r)
            u.s1.hs[(w * 16 + q * 4 + r) * 68 + nt * 16 + r15] = acc[nt][r];
    __syncthreads();

    // aggregation: thread -> node n = tid>>2, channel quarter oq (16 ch)
    int n = tid >> 2, oq = tid & 3;
    float a2[16];
#pragma unroll
    for (int j = 0; j < 16; ++j) a2[j] = 0.f;
    int e0 = coff[n], e1 = coff[n + 1];
    for (int e = e0; e < e1; ++e) {
        int s = csrc[e]; float wg = cnrm[e];
        const f32x4* hp = (const f32x4*)&u.s1.hs[s * 68 + oq * 16];
#pragma unroll
        for (int j4 = 0; j4 < 4; ++j4) {
            f32x4 hv = hp[j4];
            a2[j4 * 4 + 0] += wg * hv[0]; a2[j4 * 4 + 1] += wg * hv[1];
            a2[j4 * 4 + 2] += wg * hv[2]; a2[j4 * 4 + 3] += wg * hv[3];
        }
    }
    const f32x4* bp = (const f32x4*)&b1[oq * 16];
    float s1 = 0.f, s2 = 0.f;
    bf16x8 o0, o1;
#pragma unroll
    for (int j4 = 0; j4 < 4; ++j4) {
        f32x4 bv = bp[j4];
#pragma unroll
        for (int k = 0; k < 4; ++k) {
            float v = a2[j4 * 4 + k] + bv[k];
            s1 += v; s2 += v * v;
            if (j4 < 2) o0[j4 * 4 + k] = (bf16)v; else o1[(j4 - 2) * 4 + k] = (bf16)v;
        }
    }
    bf16* gp = g1out + ((size_t)b * 4096 + n * 64 + oq * 16);
    *(bf16x8*)gp = o0;
    *(bf16x8*)(gp + 8) = o1;
    s1 += __shfl_xor(s1, 1); s1 += __shfl_xor(s1, 2);
    s2 += __shfl_xor(s2, 1); s2 += __shfl_xor(s2, 2);
    if (oq == 0) {
        int slot = b & (NSLOT - 1);
        atomicAdd(&part1[(slot * 64 + n) * 2 + 0], s1);
        atomicAdd(&part1[(slot * 64 + n) * 2 + 1], s2);
    }
}

// ---------------- BN stats reduce: partials -> scale/shift per node ----------------
__global__ __launch_bounds__(64) void k_bnstats(
    const float* __restrict__ part,       // [NSLOT][64][2]
    const float* __restrict__ gamma, const float* __restrict__ beta,
    float* __restrict__ scale, float* __restrict__ shift, float inv_count)
{
    int n = blockIdx.x, t = threadIdx.x;
    float s1 = part[(t * 64 + n) * 2] + part[((t + 64) * 64 + n) * 2];
    float s2 = part[(t * 64 + n) * 2 + 1] + part[((t + 64) * 64 + n) * 2 + 1];
#pragma unroll
    for (int o = 32; o > 0; o >>= 1) { s1 += __shfl_down(s1, o); s2 += __shfl_down(s2, o); }
    if (t == 0) {
        float mean = s1 * inv_count;
        float var = s2 * inv_count - mean * mean;
        float sc = gamma[n] * rsqrtf(var + EPSBN);
        scale[n] = sc;
        shift[n] = beta[n] - mean * sc;
    }
}

// ---------------- K3: BN1+relu -> GCN layer 2 -> stats ----------------
__global__ __launch_bounds__(256) void k3_gcn2(
    const bf16* __restrict__ g1out,       // [B][64][64]
    const float* __restrict__ W2,         // [32][64]
    const float* __restrict__ b2,
    const float* __restrict__ scale1, const float* __restrict__ shift1,
    const int* __restrict__ g_off, const int* __restrict__ g_src,
    const float* __restrict__ g_nrm,
    bf16* __restrict__ g2out,             // [B][64][32]
    float* __restrict__ part2)
{
    __shared__ bf16 ya[64 * 72];
    __shared__ bf16 wb[32 * 72];
    __shared__ float hs[64 * 36];
    __shared__ int coff[N_ + 1];
    __shared__ int csrc[TOT_E];
    __shared__ float cnrm[TOT_E];
    __shared__ float ss1[64], sh1[64];

    int tid = threadIdx.x; int b = blockIdx.x;
    if (tid < 64) { ss1[tid] = scale1[tid]; sh1[tid] = shift1[tid]; }
    for (int i = tid; i <= N_; i += 256) coff[i] = g_off[i];
    for (int i = tid; i < TOT_E; i += 256) { csrc[i] = g_src[i]; cnrm[i] = g_nrm[i]; }
    for (int i = tid; i < 32 * 64; i += 256) {
        int o = i >> 6, f = i & 63;
        wb[o * 72 + f] = (bf16)W2[i];
    }
    __syncthreads();
    const bf16* gb = g1out + (size_t)b * 4096;
    for (int i = tid; i < 4096; i += 256) {
        int n = i >> 6;
        float v = (float)gb[i];
        float y = fmaxf(fmaf(ss1[n], v, sh1[n]), 0.f);
        ya[n * 72 + (i & 63)] = (bf16)y;
    }
    __syncthreads();

    int w = tid >> 6, lane = tid & 63, q = lane >> 4, r15 = lane & 15;
    f32x4 z4 = {0.f, 0.f, 0.f, 0.f};
    f32x4 acc[2] = {z4, z4};
#pragma unroll
    for (int kt = 0; kt < 2; ++kt) {
        bf16x8 a = *(const bf16x8*)&ya[(w * 16 + r15) * 72 + kt * 32 + q * 8];
#pragma unroll
        for (int nt = 0; nt < 2; ++nt) {
            bf16x8 bb = *(const bf16x8*)&wb[(nt * 16 + r15) * 72 + kt * 32 + q * 8];
            acc[nt] = __builtin_amdgcn_mfma_f32_16x16x32_bf16(a, bb, acc[nt], 0, 0, 0);
        }
    }
#pragma unroll
    for (int nt = 0; nt < 2; ++nt)
#pragma unroll
        for (int r = 0; r < 4; ++r)
            hs[(w * 16 + q * 4 + r) * 36 + nt * 16 + r15] = acc[nt][r];
    __syncthreads();

    int n = tid >> 2, oq = tid & 3;                   // 8 channels per thread
    float a2[8] = {0, 0, 0, 0, 0, 0, 0, 0};
    int e0 = coff[n], e1 = coff[n + 1];
    for (int e = e0; e < e1; ++e) {
        int s = csrc[e]; float wg = cnrm[e];
        const f32x4* hp = (const f32x4*)&hs[s * 36 + oq * 8];
        f32x4 h0 = hp[0], h1v = hp[1];
        a2[0] += wg * h0[0]; a2[1] += wg * h0[1]; a2[2] += wg * h0[2]; a2[3] += wg * h0[3];
        a2[4] += wg * h1v[0]; a2[5] += wg * h1v[1]; a2[6] += wg * h1v[2]; a2[7] += wg * h1v[3];
    }
    const f32x4* bp = (const f32x4*)&b2[oq * 8];
    f32x4 b0 = bp[0], b1v = bp[1];
    float s1 = 0.f, s2 = 0.f; bf16x8 ov;
#pragma unroll
    for (int k = 0; k < 8; ++k) {
        float bias = (k < 4) ? b0[k] : b1v[k - 4];
        float v = a2[k] + bias;
        s1 += v; s2 += v * v;
        ov[k] = (bf16)v;
    }
    *(bf16x8*)(g2out + ((size_t)b * 2048 + n * 32 + oq * 8)) = ov;
    s1 += __shfl_xor(s1, 1); s1 += __shfl_xor(s1, 2);
    s2 += __shfl_xor(s2, 1); s2 += __shfl_xor(s2, 2);
    if (oq == 0) {
        int slot = b & (NSLOT - 1);
        atomicAdd(&part2[(slot * 64 + n) * 2 + 0], s1);
        atomicAdd(&part2[(slot * 64 + n) * 2 + 1], s2);
    }
}

// ---------------- K6: MLP1  h1 = relu(x_fp @ Wl1^T + bl1), bf16 MFMA ----------------
__global__ __launch_bounds__(256) void k6_mlp1(
    const float* __restrict__ A,          // [4096][2048]
    const float* __restrict__ Bw,         // [400][2048]
    const float* __restrict__ bias,
    bf16* __restrict__ Cout)              // [4096][400]
{
    __shared__ bf16 As[64 * 40];
    __shared__ bf16 Bs[64 * 40];
    int tid = threadIdx.x;
    int m0 = blockIdx.x * 64, n0 = blockIdx.y * 64;
    int row = tid >> 2, seg = tid & 3;
    int w = tid >> 6, lane = tid & 63, q = lane >> 4, r15 = lane & 15;
    f32x4 z4 = {0.f, 0.f, 0.f, 0.f};
    f32x4 acc[4] = {z4, z4, z4, z4};
    const float* pA = A + (size_t)(m0 + row) * 2048 + seg * 8;
    bool bvalid = (n0 + row) < 400;
    const float* pB = Bw + (size_t)(n0 + row) * 2048 + seg * 8;

    for (int kt = 0; kt < 64; ++kt) {
        f32x4 a0 = *(const f32x4*)(pA);
        f32x4 a1 = *(const f32x4*)(pA + 4);
        bf16x8 apk;
        apk[0] = (bf16)a0[0]; apk[1] = (bf16)a0[1]; apk[2] = (bf16)a0[2]; apk[3] = (bf16)a0[3];
        apk[4] = (bf16)a1[0]; apk[5] = (bf16)a1[1]; apk[6] = (bf16)a1[2]; apk[7] = (bf16)a1[3];
        *(bf16x8*)&As[row * 40 + seg * 8] = apk;
        bf16x8 bpk;
#pragma unroll
        for (int k = 0; k < 8; ++k) bpk[k] = (bf16)0.f;
        if (bvalid) {
            f32x4 c0 = *(const f32x4*)(pB);
            f32x4 c1 = *(const f32x4*)(pB + 4);
            bpk[0] = (bf16)c0[0]; bpk[1] = (bf16)c0[1]; bpk[2] = (bf16)c0[2]; bpk[3] = (bf16)c0[3];
            bpk[4] = (bf16)c1[0]; bpk[5] = (bf16)c1[1]; bpk[6] = (bf16)c1[2]; bpk[7] = (bf16)c1[3];
        }
        *(bf16x8*)&Bs[row * 40 + seg * 8] = bpk;
        pA += 32; pB += 32;
        __syncthreads();
        bf16x8 a = *(const bf16x8*)&As[(w * 16 + r15) * 40 + q * 8];
#pragma unroll
        for (int nt = 0; nt < 4; ++nt) {
            bf16x8 bb = *(const bf16x8*)&Bs[(nt * 16 + r15) * 40 + q * 8];
            acc[nt] = __builtin_amdgcn_mfma_f32_16x16x32_bf16(a, bb, acc[nt], 0, 0, 0);
        }
        __syncthreads();
    }
#pragma unroll
    for (int nt = 0; nt < 4; ++nt)
#pragma unroll
        for (int r = 0; r < 4; ++r) {
            int mm = m0 + w * 16 + q * 4 + r;
            int nn = n0 + nt * 16 + r15;
            if (nn < 400) {
                float v = fmaxf(acc[nt][r] + bias[nn], 0.f);
                Cout[(size_t)mm * 400 + nn] = (bf16)v;
            }
        }
}

// ---------------- K7: MLP2  h2 = relu(h1 @ Wl2^T + bl2) ----------------
__global__ __launch_bounds__(256) void k7_mlp2(
    const bf16* __restrict__ A,           // [4096][400]
    const float* __restrict__ Bw,         // [64][400]
    const float* __restrict__ bias,
    float* __restrict__ Cout)             // [4096][64]
{
    __shared__ bf16 As[64 * 40];
    __shared__ bf16 Bs[64 * 40];
    int tid = threadIdx.x;
    int m0 = blockIdx.x * 64;
    int row = tid >> 2, seg = tid & 3;
    int w = tid >> 6, lane = tid & 63, q = lane >> 4, r15 = lane & 15;
    f32x4 z4 = {0.f, 0.f, 0.f, 0.f};
    f32x4 acc[4] = {z4, z4, z4, z4};

    for (int kt = 0; kt < 13; ++kt) {                 // K=400 padded to 416
        int k0 = kt * 32 + seg * 8;
        bf16x8 apk;
#pragma unroll
        for (int k = 0; k < 8; ++k) apk[k] = (bf16)0.f;
        if (k0 < 400) apk = *(const bf16x8*)(A + (size_t)(m0 + row) * 400 + k0);
        *(bf16x8*)&As[row * 40 + seg * 8] = apk;
        bf16x8 bpk;
#pragma unroll
        for (int k = 0; k < 8; ++k) bpk[k] = (bf16)0.f;
        if (k0 < 400) {
            f32x4 c0 = *(const f32x4*)(Bw + row * 400 + k0);
            f32x4 c1 = *(const f32x4*)(Bw + row * 400 + k0 + 4);
            bpk[0] = (bf16)c0[0]; bpk[1] = (bf16)c0[1]; bpk[2] = (bf16)c0[2]; bpk[3] = (bf16)c0[3];
            bpk[4] = (bf16)c1[0]; bpk[5] = (bf16)c1[1]; bpk[6] = (bf16)c1[2]; bpk[7] = (bf16)c1[3];
        }
        *(bf16x8*)&Bs[row * 40 + seg * 8] = bpk;
        __syncthreads();
        bf16x8 a = *(const bf16x8*)&As[(w * 16 + r15) * 40 + q * 8];
#pragma unroll
        for (int nt = 0; nt < 4; ++nt) {
            bf16x8 bb = *(const bf16x8*)&Bs[(nt * 16 + r15) * 40 + q * 8];
            acc[nt] = __builtin_amdgcn_mfma_f32_16x16x32_bf16(a, bb, acc[nt], 0, 0, 0);
        }
        __syncthreads();
    }
#pragma unroll
    for (int nt = 0; nt < 4; ++nt)
#pragma unroll
        for (int r = 0; r < 4; ++r) {
            int mm = m0 + w * 16 + q * 4 + r;
            int nn = nt * 16 + r15;
            float v = fmaxf(acc[nt][r] + bias[nn], 0.f);
            Cout[(size_t)mm * 64 + nn] = v;
        }
}

// ---------------- K8: BN2+relu+maxpool + concat + FC ----------------
__global__ __launch_bounds__(256) void k8_final(
    const bf16* __restrict__ g2out,       // [4096][64][32]
    const float* __restrict__ scale2, const float* __restrict__ shift2,
    const float* __restrict__ h2,         // [4096][64]
    const float* __restrict__ Wfc,        // [2][96]
    const float* __restrict__ bfc,
    float* __restrict__ out)              // [4096][2]
{
    __shared__ float s2s[64], sh2s[64];
    int tid = threadIdx.x;
    if (tid < 64) { s2s[tid] = scale2[tid]; sh2s[tid] = shift2[tid]; }
    __syncthreads();
    int w = tid >> 6, lane = tid & 63;
    int b = blockIdx.x * 4 + w;
    int c = lane & 31, half = lane >> 5;
    const bf16* gb = g2out + (size_t)b * 2048;
    float mx = 0.f;                                   // relu => max >= 0
    for (int i = 0; i < 32; ++i) {
        int n = half * 32 + i;
        float v = (float)gb[n * 32 + c];
        float val = fmaf(s2s[n], v, sh2s[n]);
        mx = fmaxf(mx, val);
    }
    mx = fmaxf(mx, __shfl_xor(mx, 32));               // pooled[c] on all lanes
    float h2v = h2[(size_t)b * 64 + lane];
#pragma unroll
    for (int o = 0; o < 2; ++o) {
        float t = h2v * Wfc[o * 96 + 32 + lane];
        if (half == 0) t += mx * Wfc[o * 96 + c];
#pragma unroll
        for (int off = 32; off > 0; off >>= 1) t += __shfl_xor(t, off);
        if (lane == 0) out[(size_t)b * 2 + o] = t + bfc[o];
    }
}

extern "C" void kernel_launch(void* const* d_in, const int* in_sizes, int n_in,
                              void* d_out, int out_size, void* d_ws, size_t ws_size,
                              hipStream_t stream)
{
    const float* x_fp   = (const float*)d_in[0];
    const float* x_node = (const float*)d_in[1];
    const int*   edge   = (const int*)d_in[2];
    const float* W1     = (const float*)d_in[3];
    const float* b1     = (const float*)d_in[4];
    const float* g1     = (const float*)d_in[5];
    const float* be1    = (const float*)d_in[6];
    const float* W2     = (const float*)d_in[7];
    const float* b2     = (const float*)d_in[8];
    const float* g2     = (const float*)d_in[9];
    const float* be2    = (const float*)d_in[10];
    const float* Wl1    = (const float*)d_in[11];
    const float* bl1    = (const float*)d_in[12];
    const float* Wl2    = (const float*)d_in[13];
    const float* bl2    = (const float*)d_in[14];
    const float* Wfc    = (const float*)d_in[15];
    const float* bfc    = (const float*)d_in[16];
    float* out = (float*)d_out;

    char* ws = (char*)d_ws;
    int*   csr_off = (int*)(ws);                      // 260 B
    int*   csr_src = (int*)(ws + 512);                // 2304 B
    float* csr_nrm = (float*)(ws + 3072);             // 2304 B
    float* scale1  = (float*)(ws + 5632);
    float* shift1  = (float*)(ws + 5888);
    float* scale2  = (float*)(ws + 6144);
    float* shift2  = (float*)(ws + 6400);
    float* part1   = (float*)(ws + 8192);             // 65536 B
    float* part2   = (float*)(ws + 8192 + 65536);     // 65536 B
    bf16*  g1out   = (bf16*)(ws + 139264);            // 33554432 B
    bf16*  g2out   = (bf16*)(ws + 33693696ull);       // 16777216 B
    bf16*  h1      = (bf16*)(ws + 50470912ull);       // 3276800 B
    float* h2      = (float*)(ws + 53747712ull);      // 1048576 B

    k0_prep<<<dim3(64), dim3(256), 0, stream>>>(edge, part1, csr_off, csr_src, csr_nrm);
    k1_gcn1<<<dim3(4096), dim3(256), 0, stream>>>(x_node, W1, b1, csr_off, csr_src, csr_nrm,
                                                  g1out, part1);
    k_bnstats<<<dim3(64), dim3(64), 0, stream>>>(part1, g1, be1, scale1, shift1,
                                                 1.f / (4096.f * 64.f));
    k3_gcn2<<<dim3(4096), dim3(256), 0, stream>>>(g1out, W2, b2, scale1, shift1,
                                                  csr_off, csr_src, csr_nrm, g2out, part2);
    k_bnstats<<<dim3(64), dim3(64), 0, stream>>>(part2, g2, be2, scale2, shift2,
                                                 1.f / (4096.f * 32.f));
    k6_mlp1<<<dim3(64, 7), dim3(256), 0, stream>>>(x_fp, Wl1, bl1, h1);
    k7_mlp2<<<dim3(64), dim3(256), 0, stream>>>(h1, Wl2, bl2, h2);
    k8_final<<<dim3(1024), dim3(256), 0, stream>>>(g2out, scale2, shift2, h2, Wfc, bfc, out);
}

// Round 2
// 265.105 us; speedup vs baseline: 1.1471x; 1.1471x over previous
//
#include <hip/hip_runtime.h>
#include <hip/hip_bf16.h>
#include <math.h>

typedef __bf16 bf16;
typedef __attribute__((ext_vector_type(8))) __bf16 bf16x8;
typedef __attribute__((ext_vector_type(4))) __bf16 bf16x4;
typedef __attribute__((ext_vector_type(4))) float f32x4;

#define EPSBN 1e-5f
#define B_    4096
#define N_    64
#define FIN_  67
#define E_    512
#define TOT_E 576
#define NSLOT 128

// ---------------- K0: build CSR (by dst) + norm, zero stat partials ----------------
__global__ __launch_bounds__(256) void k0_prep(const int* __restrict__ edge,
    float* __restrict__ partials,          // NSLOT*64*2 * 2 layers, contiguous
    int* __restrict__ g_off, int* __restrict__ g_src, float* __restrict__ g_nrm)
{
    int tid = threadIdx.x;
    for (int i = blockIdx.x * 256 + tid; i < NSLOT * 64 * 4; i += gridDim.x * 256)
        partials[i] = 0.f;
    if (blockIdx.x != 0) return;

    __shared__ int ssrc[TOT_E], sdst[TOT_E];
    __shared__ int deg[N_], cnt[N_], off[N_ + 1];
    __shared__ float dinv[N_];
    for (int i = tid; i < TOT_E; i += 256) {
        int s, d;
        if (i < E_) { s = edge[i]; d = edge[E_ + i]; }
        else        { s = i - E_; d = i - E_; }      // self loops
        ssrc[i] = s; sdst[i] = d;
    }
    if (tid < N_) { deg[tid] = 0; cnt[tid] = 0; }
    __syncthreads();
    for (int i = tid; i < TOT_E; i += 256) atomicAdd(&deg[sdst[i]], 1);
    __syncthreads();
    if (tid < N_) {                                   // wave 0 only: scan
        dinv[tid] = rsqrtf((float)deg[tid]);          // deg >= 1 (self loop)
        int v = deg[tid];
        for (int o = 1; o < 64; o <<= 1) { int u = __shfl_up(v, o); if (tid >= o) v += u; }
        off[tid] = v - deg[tid];
        if (tid == 63) off[N_] = v;
    }
    __syncthreads();
    for (int i = tid; i < TOT_E; i += 256) {
        int d = sdst[i];
        int p = off[d] + atomicAdd(&cnt[d], 1);
        g_src[p] = ssrc[i];
        g_nrm[p] = dinv[ssrc[i]] * dinv[d];
    }
    if (tid <= N_) g_off[tid] = off[tid];
}

// ---------------- K1: GCN layer 1 (matmul MFMA + aggregate + bias + stats) ----------------
__global__ __launch_bounds__(256) void k1_gcn1(
    const float* __restrict__ x,          // [B][64][67]
    const float* __restrict__ W1,         // [64][67]
    const float* __restrict__ b1,
    const int* __restrict__ g_off, const int* __restrict__ g_src,
    const float* __restrict__ g_nrm,
    bf16* __restrict__ g1out,             // [B][64][64]
    float* __restrict__ part1)            // [NSLOT][64][2]
{
    __shared__ union {
        struct { bf16 xa[64 * 104]; bf16 wb[64 * 104]; } s0;  // K padded 67->96, pitch 104
        struct { float hs[64 * 68]; } s1;                     // 64x64 h, pitch 68 (16B-aligned rows)
    } u;
    __shared__ int coff[N_ + 1];
    __shared__ int csrc[TOT_E];
    __shared__ float cnrm[TOT_E];

    int tid = threadIdx.x;
    int b = blockIdx.x;
    for (int i = tid; i <= N_; i += 256) coff[i] = g_off[i];
    for (int i = tid; i < TOT_E; i += 256) { csrc[i] = g_src[i]; cnrm[i] = g_nrm[i]; }

    const float* xb = x + (size_t)b * (N_ * FIN_);
    for (int i = tid; i < N_ * FIN_; i += 256) {
        int n = i / FIN_, f = i % FIN_;
        u.s0.xa[n * 104 + f] = (bf16)xb[i];
    }
    for (int i = tid; i < N_ * FIN_; i += 256) {
        int n = i / FIN_, f = i % FIN_;
        u.s0.wb[n * 104 + f] = (bf16)W1[i];
    }
    for (int i = tid; i < 64 * 29; i += 256) {        // zero pad k = 67..95
        int n = i / 29, f = 67 + i % 29;
        u.s0.xa[n * 104 + f] = (bf16)0.f;
        u.s0.wb[n * 104 + f] = (bf16)0.f;
    }
    __syncthreads();

    int w = tid >> 6, lane = tid & 63, q = lane >> 4, r15 = lane & 15;
    f32x4 z4 = {0.f, 0.f, 0.f, 0.f};
    f32x4 acc[4] = {z4, z4, z4, z4};
    int arow = w * 16 + r15;
#pragma unroll
    for (int kt = 0; kt < 3; ++kt) {
        bf16x8 a = *(const bf16x8*)&u.s0.xa[arow * 104 + kt * 32 + q * 8];
#pragma unroll
        for (int nt = 0; nt < 4; ++nt) {
            bf16x8 bb = *(const bf16x8*)&u.s0.wb[(nt * 16 + r15) * 104 + kt * 32 + q * 8];
            acc[nt] = __builtin_amdgcn_mfma_f32_16x16x32_bf16(a, bb, acc[nt], 0, 0, 0);
        }
    }
    __syncthreads();                                  // all xa/wb reads done before hs overwrite
#pragma unroll
    for (int nt = 0; nt < 4; ++nt)
#pragma unroll
        for (int r = 0; r < 4; ++r)
            u.s1.hs[(w * 16 + q * 4 + r) * 68 + nt * 16 + r15] = acc[nt][r];
    __syncthreads();

    // aggregation: thread -> node n = tid>>2, channel quarter oq (16 ch)
    int n = tid >> 2, oq = tid & 3;
    float a2[16];
#pragma unroll
    for (int j = 0; j < 16; ++j) a2[j] = 0.f;
    int e0 = coff[n], e1 = coff[n + 1];
    for (int e = e0; e < e1; ++e) {
        int s = csrc[e]; float wg = cnrm[e];
        const f32x4* hp = (const f32x4*)&u.s1.hs[s * 68 + oq * 16];
#pragma unroll
        for (int j4 = 0; j4 < 4; ++j4) {
            f32x4 hv = hp[j4];
            a2[j4 * 4 + 0] += wg * hv[0]; a2[j4 * 4 + 1] += wg * hv[1];
            a2[j4 * 4 + 2] += wg * hv[2]; a2[j4 * 4 + 3] += wg * hv[3];
        }
    }
    const f32x4* bp = (const f32x4*)&b1[oq * 16];
    float s1 = 0.f, s2 = 0.f;
    bf16x8 o0, o1;
#pragma unroll
    for (int j4 = 0; j4 < 4; ++j4) {
        f32x4 bv = bp[j4];
#pragma unroll
        for (int k = 0; k < 4; ++k) {
            float v = a2[j4 * 4 + k] + bv[k];
            s1 += v; s2 += v * v;
            if (j4 < 2) o0[j4 * 4 + k] = (bf16)v; else o1[(j4 - 2) * 4 + k] = (bf16)v;
        }
    }
    bf16* gp = g1out + ((size_t)b * 4096 + n * 64 + oq * 16);
    *(bf16x8*)gp = o0;
    *(bf16x8*)(gp + 8) = o1;
    s1 += __shfl_xor(s1, 1); s1 += __shfl_xor(s1, 2);
    s2 += __shfl_xor(s2, 1); s2 += __shfl_xor(s2, 2);
    if (oq == 0) {
        int slot = b & (NSLOT - 1);
        atomicAdd(&part1[(slot * 64 + n) * 2 + 0], s1);
        atomicAdd(&part1[(slot * 64 + n) * 2 + 1], s2);
    }
}

// ---------------- BN stats reduce: partials -> scale/shift per node ----------------
__global__ __launch_bounds__(64) void k_bnstats(
    const float* __restrict__ part,       // [NSLOT][64][2]
    const float* __restrict__ gamma, const float* __restrict__ beta,
    float* __restrict__ scale, float* __restrict__ shift, float inv_count)
{
    int n = blockIdx.x, t = threadIdx.x;
    float s1 = part[(t * 64 + n) * 2] + part[((t + 64) * 64 + n) * 2];
    float s2 = part[(t * 64 + n) * 2 + 1] + part[((t + 64) * 64 + n) * 2 + 1];
#pragma unroll
    for (int o = 32; o > 0; o >>= 1) { s1 += __shfl_down(s1, o); s2 += __shfl_down(s2, o); }
    if (t == 0) {
        float mean = s1 * inv_count;
        float var = s2 * inv_count - mean * mean;
        float sc = gamma[n] * rsqrtf(var + EPSBN);
        scale[n] = sc;
        shift[n] = beta[n] - mean * sc;
    }
}

// ---------------- K3: BN1+relu -> GCN layer 2 -> stats ----------------
__global__ __launch_bounds__(256) void k3_gcn2(
    const bf16* __restrict__ g1out,       // [B][64][64]
    const float* __restrict__ W2,         // [32][64]
    const float* __restrict__ b2,
    const float* __restrict__ scale1, const float* __restrict__ shift1,
    const int* __restrict__ g_off, const int* __restrict__ g_src,
    const float* __restrict__ g_nrm,
    bf16* __restrict__ g2out,             // [B][64][32]
    float* __restrict__ part2)
{
    __shared__ bf16 ya[64 * 72];
    __shared__ bf16 wb[32 * 72];
    __shared__ float hs[64 * 36];
    __shared__ int coff[N_ + 1];
    __shared__ int csrc[TOT_E];
    __shared__ float cnrm[TOT_E];
    __shared__ float ss1[64], sh1[64];

    int tid = threadIdx.x; int b = blockIdx.x;
    if (tid < 64) { ss1[tid] = scale1[tid]; sh1[tid] = shift1[tid]; }
    for (int i = tid; i <= N_; i += 256) coff[i] = g_off[i];
    for (int i = tid; i < TOT_E; i += 256) { csrc[i] = g_src[i]; cnrm[i] = g_nrm[i]; }
    for (int i = tid; i < 32 * 64; i += 256) {
        int o = i >> 6, f = i & 63;
        wb[o * 72 + f] = (bf16)W2[i];
    }
    __syncthreads();
    const bf16* gb = g1out + (size_t)b * 4096;
    for (int i = tid; i < 4096; i += 256) {
        int n = i >> 6;
        float v = (float)gb[i];
        float y = fmaxf(fmaf(ss1[n], v, sh1[n]), 0.f);
        ya[n * 72 + (i & 63)] = (bf16)y;
    }
    __syncthreads();

    int w = tid >> 6, lane = tid & 63, q = lane >> 4, r15 = lane & 15;
    f32x4 z4 = {0.f, 0.f, 0.f, 0.f};
    f32x4 acc[2] = {z4, z4};
#pragma unroll
    for (int kt = 0; kt < 2; ++kt) {
        bf16x8 a = *(const bf16x8*)&ya[(w * 16 + r15) * 72 + kt * 32 + q * 8];
#pragma unroll
        for (int nt = 0; nt < 2; ++nt) {
            bf16x8 bb = *(const bf16x8*)&wb[(nt * 16 + r15) * 72 + kt * 32 + q * 8];
            acc[nt] = __builtin_amdgcn_mfma_f32_16x16x32_bf16(a, bb, acc[nt], 0, 0, 0);
        }
    }
#pragma unroll
    for (int nt = 0; nt < 2; ++nt)
#pragma unroll
        for (int r = 0; r < 4; ++r)
            hs[(w * 16 + q * 4 + r) * 36 + nt * 16 + r15] = acc[nt][r];
    __syncthreads();

    int n = tid >> 2, oq = tid & 3;                   // 8 channels per thread
    float a2[8] = {0, 0, 0, 0, 0, 0, 0, 0};
    int e0 = coff[n], e1 = coff[n + 1];
    for (int e = e0; e < e1; ++e) {
        int s = csrc[e]; float wg = cnrm[e];
        const f32x4* hp = (const f32x4*)&hs[s * 36 + oq * 8];
        f32x4 h0 = hp[0], h1v = hp[1];
        a2[0] += wg * h0[0]; a2[1] += wg * h0[1]; a2[2] += wg * h0[2]; a2[3] += wg * h0[3];
        a2[4] += wg * h1v[0]; a2[5] += wg * h1v[1]; a2[6] += wg * h1v[2]; a2[7] += wg * h1v[3];
    }
    const f32x4* bp = (const f32x4*)&b2[oq * 8];
    f32x4 b0 = bp[0], b1v = bp[1];
    float s1 = 0.f, s2 = 0.f; bf16x8 ov;
#pragma unroll
    for (int k = 0; k < 8; ++k) {
        float bias = (k < 4) ? b0[k] : b1v[k - 4];
        float v = a2[k] + bias;
        s1 += v; s2 += v * v;
        ov[k] = (bf16)v;
    }
    *(bf16x8*)(g2out + ((size_t)b * 2048 + n * 32 + oq * 8)) = ov;
    s1 += __shfl_xor(s1, 1); s1 += __shfl_xor(s1, 2);
    s2 += __shfl_xor(s2, 1); s2 += __shfl_xor(s2, 2);
    if (oq == 0) {
        int slot = b & (NSLOT - 1);
        atomicAdd(&part2[(slot * 64 + n) * 2 + 0], s1);
        atomicAdd(&part2[(slot * 64 + n) * 2 + 1], s2);
    }
}

// ---------------- K6: MLP1 split-K GEMM, register-prefetch pipeline ----------------
// grid (64 m-tiles, 7 n-tiles, 4 k-splits) = 1792 blocks; partials fp32.
__global__ __launch_bounds__(256) void k6_mlp1(
    const float* __restrict__ A,          // [4096][2048]
    const float* __restrict__ Bw,         // [400][2048]
    float* __restrict__ part)             // [4][4096][400]
{
    __shared__ bf16 As[64 * 36];          // pitch 36 bf16 = 72B: r15*18 mod 32 -> 16 distinct dwords
    __shared__ bf16 Bs[64 * 36];
    int tid = threadIdx.x;
    int m0 = blockIdx.x * 64, n0 = blockIdx.y * 64, ks = blockIdx.z;
    int row = tid >> 2, seg = tid & 3;
    int w = tid >> 6, lane = tid & 63, q = lane >> 4, r15 = lane & 15;
    f32x4 z4 = {0.f, 0.f, 0.f, 0.f};
    f32x4 acc[4] = {z4, z4, z4, z4};
    const float* pA = A + (size_t)(m0 + row) * 2048 + ks * 512 + seg * 8;
    bool bvalid = (n0 + row) < 400;
    const float* pB = Bw + (size_t)(n0 + row) * 2048 + ks * 512 + seg * 8;

    // prefetch tile 0 into registers
    f32x4 a0 = *(const f32x4*)pA;
    f32x4 a1 = *(const f32x4*)(pA + 4);
    f32x4 c0 = z4, c1 = z4;
    if (bvalid) { c0 = *(const f32x4*)pB; c1 = *(const f32x4*)(pB + 4); }

    for (int kt = 0; kt < 16; ++kt) {
        bf16x8 apk, bpk;
        apk[0] = (bf16)a0[0]; apk[1] = (bf16)a0[1]; apk[2] = (bf16)a0[2]; apk[3] = (bf16)a0[3];
        apk[4] = (bf16)a1[0]; apk[5] = (bf16)a1[1]; apk[6] = (bf16)a1[2]; apk[7] = (bf16)a1[3];
        bpk[0] = (bf16)c0[0]; bpk[1] = (bf16)c0[1]; bpk[2] = (bf16)c0[2]; bpk[3] = (bf16)c0[3];
        bpk[4] = (bf16)c1[0]; bpk[5] = (bf16)c1[1]; bpk[6] = (bf16)c1[2]; bpk[7] = (bf16)c1[3];
        __syncthreads();                              // prior compute done reading LDS
        *(bf16x8*)&As[row * 36 + seg * 8] = apk;
        *(bf16x8*)&Bs[row * 36 + seg * 8] = bpk;
        __syncthreads();
        if (kt < 15) {                                // issue next loads; overlap with MFMAs below
            pA += 32; pB += 32;
            a0 = *(const f32x4*)pA; a1 = *(const f32x4*)(pA + 4);
            if (bvalid) { c0 = *(const f32x4*)pB; c1 = *(const f32x4*)(pB + 4); }
        }
        bf16x8 a = *(const bf16x8*)&As[(w * 16 + r15) * 36 + q * 8];
#pragma unroll
        for (int nt = 0; nt < 4; ++nt) {
            bf16x8 bb = *(const bf16x8*)&Bs[(nt * 16 + r15) * 36 + q * 8];
            acc[nt] = __builtin_amdgcn_mfma_f32_16x16x32_bf16(a, bb, acc[nt], 0, 0, 0);
        }
    }
    float* pp = part + (size_t)ks * 1638400;
#pragma unroll
    for (int nt = 0; nt < 4; ++nt)
#pragma unroll
        for (int r = 0; r < 4; ++r) {
            int mm = m0 + w * 16 + q * 4 + r;
            int nn = n0 + nt * 16 + r15;
            if (nn < 400) pp[(size_t)mm * 400 + nn] = acc[nt][r];
        }
}

// ---------------- K6R: reduce 4 k-splits + bias + relu -> bf16 h1 ----------------
__global__ __launch_bounds__(256) void k6_reduce(
    const float* __restrict__ part,       // [4][4096][400]
    const float* __restrict__ bias,       // [400]
    bf16* __restrict__ h1)                // [4096][400]
{
    int i = blockIdx.x * 256 + threadIdx.x;           // 409600 f32x4 groups
    const f32x4* p = (const f32x4*)part;
    f32x4 s0 = p[i], s1v = p[i + 409600], s2v = p[i + 819200], s3v = p[i + 1228800];
    int nn = (i * 4) % 400;                           // 400 % 4 == 0: group stays in-row
    f32x4 bv = *(const f32x4*)&bias[nn];
    bf16x4 ov;
    ov[0] = (bf16)fmaxf(s0[0] + s1v[0] + s2v[0] + s3v[0] + bv[0], 0.f);
    ov[1] = (bf16)fmaxf(s0[1] + s1v[1] + s2v[1] + s3v[1] + bv[1], 0.f);
    ov[2] = (bf16)fmaxf(s0[2] + s1v[2] + s2v[2] + s3v[2] + bv[2], 0.f);
    ov[3] = (bf16)fmaxf(s0[3] + s1v[3] + s2v[3] + s3v[3] + bv[3], 0.f);
    *(bf16x4*)&h1[i * 4] = ov;
}

// ---------------- K7: MLP2  h2 = relu(h1 @ Wl2^T + bl2) ----------------
// 256 blocks, M=16 per block, A staged to LDS once, B streamed from regs, no K-loop barriers.
__global__ __launch_bounds__(256) void k7_mlp2(
    const bf16* __restrict__ A,           // [4096][400] bf16
    const float* __restrict__ Bw,         // [64][400] f32
    const float* __restrict__ bias,
    float* __restrict__ Cout)             // [4096][64]
{
    __shared__ bf16 As[16 * 416];         // K padded 400->416
    int tid = threadIdx.x;
    int m0 = blockIdx.x * 16;
    for (int i = tid; i < 16 * 50; i += 256) {        // 50 bf16x8 chunks per row
        int rr = i / 50, cc = (i % 50) * 8;
        *(bf16x8*)&As[rr * 416 + cc] = *(const bf16x8*)(A + (size_t)(m0 + rr) * 400 + cc);
    }
    if (tid < 32) {                                   // zero pad k = 400..415
        int rr = tid >> 1, cc = 400 + (tid & 1) * 8;
        bf16x8 z;
#pragma unroll
        for (int k = 0; k < 8; ++k) z[k] = (bf16)0.f;
        *(bf16x8*)&As[rr * 416 + cc] = z;
    }
    __syncthreads();

    int w = tid >> 6, lane = tid & 63, q = lane >> 4, r15 = lane & 15;
    f32x4 acc = {0.f, 0.f, 0.f, 0.f};
    const float* pB = Bw + (size_t)(w * 16 + r15) * 400;
#pragma unroll 4
    for (int kt = 0; kt < 13; ++kt) {
        int k0 = kt * 32 + q * 8;
        bf16x8 a = *(const bf16x8*)&As[r15 * 416 + k0];
        bf16x8 bb;
#pragma unroll
        for (int k = 0; k < 8; ++k) bb[k] = (bf16)0.f;
        if (k0 < 400) {
            f32x4 c0 = *(const f32x4*)(pB + k0);
            f32x4 c1 = *(const f32x4*)(pB + k0 + 4);
            bb[0] = (bf16)c0[0]; bb[1] = (bf16)c0[1]; bb[2] = (bf16)c0[2]; bb[3] = (bf16)c0[3];
            bb[4] = (bf16)c1[0]; bb[5] = (bf16)c1[1]; bb[6] = (bf16)c1[2]; bb[7] = (bf16)c1[3];
        }
        acc = __builtin_amdgcn_mfma_f32_16x16x32_bf16(a, bb, acc, 0, 0, 0);
    }
#pragma unroll
    for (int r = 0; r < 4; ++r) {
        int mm = m0 + q * 4 + r;
        int nn = w * 16 + r15;
        float v = fmaxf(acc[r] + bias[nn], 0.f);
        Cout[(size_t)mm * 64 + nn] = v;
    }
}

// ---------------- K8: BN2+relu+maxpool + concat + FC ----------------
__global__ __launch_bounds__(256) void k8_final(
    const bf16* __restrict__ g2out,       // [4096][64][32]
    const float* __restrict__ scale2, const float* __restrict__ shift2,
    const float* __restrict__ h2,         // [4096][64]
    const float* __restrict__ Wfc,        // [2][96]
    const float* __restrict__ bfc,
    float* __restrict__ out)              // [4096][2]
{
    __shared__ float s2s[64], sh2s[64];
    int tid = threadIdx.x;
    if (tid < 64) { s2s[tid] = scale2[tid]; sh2s[tid] = shift2[tid]; }
    __syncthreads();
    int w = tid >> 6, lane = tid & 63;
    int b = blockIdx.x * 4 + w;
    int c = lane & 31, half = lane >> 5;
    const bf16* gb = g2out + (size_t)b * 2048;
    float mx = 0.f;                                   // relu => max >= 0
    for (int i = 0; i < 32; ++i) {
        int n = half * 32 + i;
        float v = (float)gb[n * 32 + c];
        float val = fmaf(s2s[n], v, sh2s[n]);
        mx = fmaxf(mx, val);
    }
    mx = fmaxf(mx, __shfl_xor(mx, 32));               // pooled[c] on all lanes
    float h2v = h2[(size_t)b * 64 + lane];
#pragma unroll
    for (int o = 0; o < 2; ++o) {
        float t = h2v * Wfc[o * 96 + 32 + lane];
        if (half == 0) t += mx * Wfc[o * 96 + c];
#pragma unroll
        for (int off = 32; off > 0; off >>= 1) t += __shfl_xor(t, off);
        if (lane == 0) out[(size_t)b * 2 + o] = t + bfc[o];
    }
}

extern "C" void kernel_launch(void* const* d_in, const int* in_sizes, int n_in,
                              void* d_out, int out_size, void* d_ws, size_t ws_size,
                              hipStream_t stream)
{
    const float* x_fp   = (const float*)d_in[0];
    const float* x_node = (const float*)d_in[1];
    const int*   edge   = (const int*)d_in[2];
    const float* W1     = (const float*)d_in[3];
    const float* b1     = (const float*)d_in[4];
    const float* g1     = (const float*)d_in[5];
    const float* be1    = (const float*)d_in[6];
    const float* W2     = (const float*)d_in[7];
    const float* b2     = (const float*)d_in[8];
    const float* g2     = (const float*)d_in[9];
    const float* be2    = (const float*)d_in[10];
    const float* Wl1    = (const float*)d_in[11];
    const float* bl1    = (const float*)d_in[12];
    const float* Wl2    = (const float*)d_in[13];
    const float* bl2    = (const float*)d_in[14];
    const float* Wfc    = (const float*)d_in[15];
    const float* bfc    = (const float*)d_in[16];
    float* out = (float*)d_out;

    char* ws = (char*)d_ws;
    int*   csr_off = (int*)(ws);                      // 260 B
    int*   csr_src = (int*)(ws + 512);                // 2304 B
    float* csr_nrm = (float*)(ws + 3072);             // 2304 B
    float* scale1  = (float*)(ws + 5632);
    float* shift1  = (float*)(ws + 5888);
    float* scale2  = (float*)(ws + 6144);
    float* shift2  = (float*)(ws + 6400);
    float* part1   = (float*)(ws + 8192);             // 65536 B
    float* part2   = (float*)(ws + 8192 + 65536);     // 65536 B
    bf16*  g1out   = (bf16*)(ws + 139264);            // 33554432 B (dead after k3 -> reused as part6)
    float* part6   = (float*)(ws + 139264);           // 26214400 B, overlays g1out
    bf16*  g2out   = (bf16*)(ws + 33693696ull);       // 16777216 B
    bf16*  h1      = (bf16*)(ws + 50470912ull);       // 3276800 B
    float* h2      = (float*)(ws + 53747712ull);      // 1048576 B

    k0_prep<<<dim3(64), dim3(256), 0, stream>>>(edge, part1, csr_off, csr_src, csr_nrm);
    k1_gcn1<<<dim3(4096), dim3(256), 0, stream>>>(x_node, W1, b1, csr_off, csr_src, csr_nrm,
                                                  g1out, part1);
    k_bnstats<<<dim3(64), dim3(64), 0, stream>>>(part1, g1, be1, scale1, shift1,
                                                 1.f / (4096.f * 64.f));
    k3_gcn2<<<dim3(4096), dim3(256), 0, stream>>>(g1out, W2, b2, scale1, shift1,
                                                  csr_off, csr_src, csr_nrm, g2out, part2);
    k_bnstats<<<dim3(64), dim3(64), 0, stream>>>(part2, g2, be2, scale2, shift2,
                                                 1.f / (4096.f * 32.f));
    // g1out is dead now; k6 writes split-K partials into its space
    k6_mlp1<<<dim3(64, 7, 4), dim3(256), 0, stream>>>(x_fp, Wl1, part6);
    k6_reduce<<<dim3(1600), dim3(256), 0, stream>>>(part6, bl1, h1);
    k7_mlp2<<<dim3(256), dim3(256), 0, stream>>>(h1, Wl2, bl2, h2);
    k8_final<<<dim3(1024), dim3(256), 0, stream>>>(g2out, scale2, shift2, h2, Wfc, bfc, out);
}